// Round 11
// baseline (1458.255 us; speedup 1.0000x reference)
//
#include <hip/hip_runtime.h>
#include <math.h>

// LatentDynamics: out[b,t,:] = scan of h' = tanh(h*leak + sigmoid(h@Wh^T + z_t@Wz^T + b)*z_t)
// B=64, T=512, D=1024.
//
// Phase 0 (k_prep):  fp32->f16 W split (Wh/Wz); init exchange slots (parity0 = h0 tag 0,
//                    parity1 = sentinel) -- re-run every launch (graph-safe).
// Phase 1 (k_recur): FUSED. 256 persistent WGs = 16 groups (4 batches) x 16 ranks (64 j).
//                    Both Wh and Wz quarter-slices register-resident (256 VGPR/lane).
//                    Per step: stage z_t quarter (prefetched last step) -> issue h-poll ->
//                    32 z-MFMAs under poll flight -> per-producer chunks {poll 2 u64,
//                    stage, 8 h-MFMAs} -> cross-wave k-reduce (padded LDS, 1 barrier) ->
//                    epilogue(+bias) -> publish -> prefetch z(t+1)/Z(t+1) -> out store.
//                    Fence-free tagged u64 slots ([tag32|2xf16], relaxed agent atomics).

#define D_ 1024
#define B_ 64
#define T_ 512

typedef _Float16 f16;
typedef _Float16 f16x8 __attribute__((ext_vector_type(8)));
typedef _Float16 f16x4 __attribute__((ext_vector_type(4)));
typedef float f32x4 __attribute__((ext_vector_type(4)));
typedef unsigned long long u64;

// workspace layout (bytes); total 4,718,592 (4.5 MB)
#define WS_WH16  0L
#define WS_WZ16  2097152L
#define WS_SLOTS 4194304L
// slots: u64[2][64][512]  (parity, batch, j-pair)

// ---------------------------------------------------------------- phase 0
__global__ __launch_bounds__(256) void k_prep(
    const float* __restrict__ W, const float* __restrict__ h0,
    f16* __restrict__ wh16, f16* __restrict__ wz16, u64* __restrict__ slots) {
  const int tid = blockIdx.x * 256 + threadIdx.x;  // grid = 2048*256 = 524288
  {
    const long e = (long)tid * 4;
    const long j = e >> 11, c = e & 2047;
    float4 v = *(const float4*)(W + e);
    f16x4 o = {(f16)v.x, (f16)v.y, (f16)v.z, (f16)v.w};
    f16* dst = (c < D_) ? (wh16 + j * D_ + c) : (wz16 + j * D_ + (c - D_));
    *(f16x4*)dst = o;
  }
  if (tid < 65536) {
    if (tid < 32768) {  // parity 0 <- h0, tag 0
      const int b = tid >> 9, p = tid & 511;
      f16 fa = (f16)h0[(long)b * D_ + 2 * p];
      f16 fb = (f16)h0[(long)b * D_ + 2 * p + 1];
      unsigned u = (unsigned)*(unsigned short*)&fa |
                   ((unsigned)*(unsigned short*)&fb << 16);
      slots[tid] = (u64)u;
    } else {
      slots[tid] = 0xFFFFFFFF00000000ull;  // parity 1 sentinel
    }
  }
}

// ---------------------------------------------------------------- phase 1
// 256 WGs x 256 threads (1/CU). g = (bid&7)*2 + ((bid>>3)&1), rk = bid>>4.
// Batches b0..b0+4 (b0=g*4), cols j0..j0+64 (j0=rk*64). Wave w = k-quarter.
// LDS: Hb 8 KB (h quarters) + Hz 8 KB (z quarters) + Rd[2] 10 KB = 26 KB.
__global__ __launch_bounds__(256, 1) void k_recur(
    const f16* __restrict__ wh16, const f16* __restrict__ wz16, u64* slots,
    const float* __restrict__ z, const float* __restrict__ h0,
    const float* __restrict__ alpha, const float* __restrict__ bias,
    float* __restrict__ out) {
  __shared__ char Hb[8192];
  __shared__ char Hz[8192];
  __shared__ char Rd[2][5120];  // [par][kq*1280 + r*320 + n*64 + col*4]

  const int tid = threadIdx.x, lane = tid & 63, w = tid >> 6;
  const int bid = blockIdx.x;
  const int g = (bid & 7) * 2 + ((bid >> 3) & 1);
  const int rk = bid >> 4;
  const int j0 = rk * 64, b0 = g * 4;

  // register-resident Wh/Wz B-frags: wave w, n-tile n, k-step kt
  // elem: W*[col = j0+n*16+(lane&15)][k = w*256 + kt*32 + (lane>>4)*8 + e]
  f16x8 bfr[32], bfz[32];
  {
    const long wo = (long)(j0 + (lane & 15)) * D_ + w * 256 + (lane >> 4) * 8;
    const f16* wb = wh16 + wo;
    const f16* wzb = wz16 + wo;
#pragma unroll
    for (int n = 0; n < 4; ++n)
#pragma unroll
      for (int kt = 0; kt < 8; ++kt) {
        bfr[n * 8 + kt] = *(const f16x8*)(wb + (long)n * 16 * D_ + kt * 32);
        bfz[n * 8 + kt] = *(const f16x8*)(wzb + (long)n * 16 * D_ + kt * 32);
      }
  }

  const int jj = j0 + lane;
  const float lk = 1.0f - alpha[jj];
  const float bi = bias[jj];
  float hp = h0[(long)(b0 + w) * D_ + jj];

  const int row = lane & 3, g8 = lane >> 4;

  // pre-loop prefetch: z tile for t=0 (wave quarter) + Z scalar for t=0
  float4 zreg[4];
#pragma unroll
  for (int cz = 0; cz < 4; ++cz)
    zreg[cz] = *(const float4*)(z + ((long)(b0 + cz) * T_) * D_ + w * 256 + lane * 4);
  float Z = z[((long)(b0 + w) * T_) * D_ + jj];

  for (int t = 0; t < T_; ++t) {
    // ---- 1. issue h-poll bulk loads: chunk c = producer rank 4w+c ----
    const u64* cur = slots + (long)(t & 1) * 32768 + (long)b0 * 512 + w * 128;
    u64 vv[8];
#pragma unroll
    for (int i = 0; i < 8; ++i) {
      const int c = i >> 1, b = (lane >> 5) + 2 * (i & 1);
      vv[i] = __hip_atomic_load(cur + b * 512 + c * 32 + (lane & 31),
                                __ATOMIC_RELAXED, __HIP_MEMORY_SCOPE_AGENT);
    }

    // ---- 2. cvt + stage z quarter (prefetched last step) ----
#pragma unroll
    for (int cz = 0; cz < 4; ++cz) {
      const float4 v = zreg[cz];
      f16 pa = (f16)v.x, pb = (f16)v.y, pc = (f16)v.z, pd = (f16)v.w;
      const unsigned lo = (unsigned)*(unsigned short*)&pa |
                          ((unsigned)*(unsigned short*)&pb << 16);
      const unsigned hi = (unsigned)*(unsigned short*)&pc |
                          ((unsigned)*(unsigned short*)&pd << 16);
      const u64 pv = (u64)lo | ((u64)hi << 32);
      *(u64*)(Hz + ((w * 2048 + cz * 512 + lane * 8) ^ ((cz & 1) << 6))) = pv;
    }

    // ---- 3. z-MFMAs (execute while poll loads are in flight) ----
    f32x4 acc[4] = {{0,0,0,0},{0,0,0,0},{0,0,0,0},{0,0,0,0}};
#pragma unroll
    for (int kt = 0; kt < 8; ++kt) {
      f16x8 az = *(const f16x8*)(
          Hz + ((w * 2048 + row * 512 + kt * 64 + g8 * 16) ^ ((row & 1) << 6)));
#pragma unroll
      for (int n = 0; n < 4; ++n)
        acc[n] = __builtin_amdgcn_mfma_f32_16x16x32_f16(az, bfz[n * 8 + kt], acc[n], 0, 0, 0);
    }

    // ---- 4. per-producer chunks: validate -> stage -> 2 kt x 4 n MFMAs ----
#pragma unroll
    for (int c = 0; c < 4; ++c) {
      unsigned p2 = 3u;
      for (int guard = 0; p2 && guard < (1 << 18); ++guard) {
        if ((p2 & 1u) && (unsigned)(vv[2 * c] >> 32) == (unsigned)t) p2 &= ~1u;
        if ((p2 & 2u) && (unsigned)(vv[2 * c + 1] >> 32) == (unsigned)t) p2 &= ~2u;
        if (p2 & 1u)
          vv[2 * c] = __hip_atomic_load(cur + ((lane >> 5) + 0) * 512 + c * 32 + (lane & 31),
                                        __ATOMIC_RELAXED, __HIP_MEMORY_SCOPE_AGENT);
        if (p2 & 2u)
          vv[2 * c + 1] = __hip_atomic_load(cur + ((lane >> 5) + 2) * 512 + c * 32 + (lane & 31),
                                            __ATOMIC_RELAXED, __HIP_MEMORY_SCOPE_AGENT);
      }
#pragma unroll
      for (int i2 = 0; i2 < 2; ++i2) {
        const int b = (lane >> 5) + 2 * i2;
        *(unsigned*)(Hb + ((w * 2048 + b * 512 + (c * 32 + (lane & 31)) * 4) ^
                           ((b & 1) << 6))) = (unsigned)vv[2 * c + i2];
      }
#pragma unroll
      for (int k2 = 0; k2 < 2; ++k2) {
        const int kt = 2 * c + k2;
        f16x8 af = *(const f16x8*)(
            Hb + ((w * 2048 + row * 512 + kt * 64 + g8 * 16) ^ ((row & 1) << 6)));
#pragma unroll
        for (int n = 0; n < 4; ++n)
          acc[n] = __builtin_amdgcn_mfma_f32_16x16x32_f16(af, bfr[n * 8 + kt], acc[n], 0, 0, 0);
      }
    }

    // ---- 5. red write: lane stores reg r=g8 (dup C-rows make this complete) ----
    char* rd = Rd[t & 1];
#pragma unroll
    for (int n = 0; n < 4; ++n) {
      const f32x4 v = acc[n];
      const float val = (g8 & 1) ? ((g8 & 2) ? v[3] : v[1])
                                 : ((g8 & 2) ? v[2] : v[0]);
      *(float*)(rd + w * 1280 + g8 * 320 + n * 64 + (lane & 15) * 4) = val;
    }
    __syncthreads();  // the ONLY barrier per step

    // ---- 6. reduce + epilogue: thread owns (b0+w, jj) ----
    float pre = bi;
#pragma unroll
    for (int kq = 0; kq < 4; ++kq)
      pre += *(const float*)(rd + kq * 1280 + w * 320 + lane * 4);

    const float gg = __builtin_amdgcn_rcpf(1.0f + __expf(-pre));
    float y = 2.0f * (hp * lk + gg * Z);
    y = fminf(fmaxf(y, -30.0f), 30.0f);
    const float ex = __expf(y);
    const float hn = (ex - 1.0f) * __builtin_amdgcn_rcpf(ex + 1.0f);
    hp = hn;

    // ---- 7. publish first (critical path) ----
    const float q = __shfl_xor(hn, 1);
    if (!(lane & 1)) {
      f16 pa = (f16)hn, pb = (f16)q;
      const unsigned u = (unsigned)*(unsigned short*)&pa |
                         ((unsigned)*(unsigned short*)&pb << 16);
      const u64 val = (((u64)(unsigned)(t + 1)) << 32) | (u64)u;
      __hip_atomic_store(
          slots + (long)((t + 1) & 1) * 32768 + (long)(b0 + w) * 512 + (jj >> 1),
          val, __ATOMIC_RELAXED, __HIP_MEMORY_SCOPE_AGENT);
    }

    // ---- 8. prefetch next z tile / Z (HBM latency hides in comm gap) ----
    const int tn = (t + 1 < T_) ? t + 1 : t;
#pragma unroll
    for (int cz = 0; cz < 4; ++cz)
      zreg[cz] = *(const float4*)(z + ((long)(b0 + cz) * T_ + tn) * D_ + w * 256 + lane * 4);
    const long offn = ((long)(b0 + w) * T_ + tn) * D_ + jj;
    const long off = ((long)(b0 + w) * T_ + t) * D_ + jj;
    const float Znext = z[offn];
    out[off] = hn;
    Z = Znext;
  }
}

// ---------------------------------------------------------------- launcher
extern "C" void kernel_launch(void* const* d_in, const int* in_sizes, int n_in,
                              void* d_out, int out_size, void* d_ws, size_t ws_size,
                              hipStream_t stream) {
  const float* h_t = (const float*)d_in[0];
  const float* z = (const float*)d_in[1];
  const float* W = (const float*)d_in[2];
  const float* bias = (const float*)d_in[3];
  const float* alpha = (const float*)d_in[4];
  float* out = (float*)d_out;
  char* ws = (char*)d_ws;
  f16* wh16 = (f16*)(ws + WS_WH16);
  f16* wz16 = (f16*)(ws + WS_WZ16);
  u64* slots = (u64*)(ws + WS_SLOTS);
  // requires ws_size >= 4,718,592 bytes

  k_prep<<<dim3(2048), dim3(256), 0, stream>>>(W, h_t, wh16, wz16, slots);
  k_recur<<<dim3(256), dim3(256), 0, stream>>>(wh16, wz16, slots, z, h_t, alpha, bias, out);
}